// Round 1
// baseline (739.731 us; speedup 1.0000x reference)
//
#include <hip/hip_runtime.h>
#include <hip/hip_bf16.h>

// Problem: out[b,q,d] = softmax(e[b,q,:]) @ sent[b,:,d]
// B=64, L2=1024, L1=1024, D=768, fp32 in/out.
// Softmax fused into GEMM via shift-invariance:
//   out = (exp(e) @ sent) / rowsum(exp(e))      (e ~ N(0,1): no overflow)
// Workspace: sT (bf16) [B][D][L1] @ 0 (100,663,296 B)
//
// GEMM is the 256x256 phase-scheduled template (T2 swizzle + T3/T4 counted
// vmcnt + T5 setprio), exp fused into the A-staging (reg-staged), BK=64,
// double-buffered LDS (128 KiB, 1 block/CU), 8 waves, per-wave 128x64 out.

#define B_  64
#define L1_ 1024
#define L2_ 1024
#define D_  768

typedef __attribute__((ext_vector_type(8))) short short8;
typedef __attribute__((ext_vector_type(4))) float f32x4;
typedef __attribute__((ext_vector_type(8))) unsigned short ushort8;

static __device__ __forceinline__ unsigned short f2bf(float x) {
  union { float f; unsigned int u; } c; c.f = x;
  unsigned int r = c.u + 0x7FFF + ((c.u >> 16) & 1);  // RNE
  return (unsigned short)(r >> 16);
}

// ---------------- transpose + cast: sent[b][l][d] f32 -> sT[b][d][l] bf16 ---
__global__ __launch_bounds__(256) void transpose_cast_kernel(const float* __restrict__ sent,
                                                             unsigned short* __restrict__ sT) {
  __shared__ unsigned short tile[64][66];
  const int b  = blockIdx.z;
  const int l0 = blockIdx.y << 6;
  const int d0 = blockIdx.x << 6;
  const int t  = threadIdx.x;
  const float* sp = sent + ((size_t)b * L1_ + l0) * D_ + d0;
  const int c4 = (t & 15) << 2;
  const int r0 = t >> 4;
#pragma unroll
  for (int p = 0; p < 4; ++p) {
    const int r = r0 + (p << 4);
    float4 v = *reinterpret_cast<const float4*>(sp + (size_t)r * D_ + c4);
    tile[r][c4 + 0] = f2bf(v.x);
    tile[r][c4 + 1] = f2bf(v.y);
    tile[r][c4 + 2] = f2bf(v.z);
    tile[r][c4 + 3] = f2bf(v.w);
  }
  __syncthreads();
  unsigned short* op = sT + ((size_t)b * D_ + d0) * L1_ + l0;
  const int l8  = (t & 7) << 3;
  const int dd0 = t >> 3;
#pragma unroll
  for (int p = 0; p < 2; ++p) {
    const int d = dd0 + (p << 5);
    ushort8 w;
#pragma unroll
    for (int j = 0; j < 8; ++j) w[j] = tile[l8 + j][d];
    *reinterpret_cast<ushort8*>(op + (size_t)d * L1_ + l8) = w;
  }
}

// ------- fused GEMM: out[b] = (exp(e[b]) @ sT[b]^T) / rowsum(exp(e[b])) ----
#define BM 256
#define BN 256
#define BK 64
#define NT    (L1_ / BK)              // 16 K-tiles
#define MT    (L2_ / BM)              // 4
#define NTL   (D_ / BN)               // 3
#define NWG   (B_ * MT * NTL)         // 768 (divisible by 8)

#define GLOAD(gp, lp) \
  __builtin_amdgcn_global_load_lds((const __attribute__((address_space(1))) char*)(gp), \
                                   (__attribute__((address_space(3))) char*)(lp), 16, 0, 0)

// stage B K-tile T into Bs[BUF]: linear LDS dest, inverse-swizzled source.
// 4 rounds x (512 thr x 16B) = 32 KiB. Per-lane source slot precomputed (Bsrc).
#define SBST(T, BUF) do { \
    const int _tb = (T) & (NT - 1); \
    _Pragma("unroll") \
    for (int c_ = 0; c_ < 4; ++c_) \
      GLOAD(Bsrc + (size_t)c_ * 64 * L1_ + _tb * BK, &Bs[BUF][(c_ * 64 + w * 8) * BK]); \
  } while (0)

// A K-tile T f32 loads -> regs (thread owns row rA, k-half kh: 32 floats)
#define LOADA(T) do { \
    const int _ta = (T) & (NT - 1); \
    _Pragma("unroll") \
    for (int j_ = 0; j_ < 8; ++j_) \
      ar[j_] = *reinterpret_cast<const float4*>(Asrc + _ta * BK + j_ * 4); \
  } while (0)

// exp + cvt + swizzled ds_write of the A regs into As[BUF]; row-partial psum.
#define EXPWRITE(VALID, BUF) do { if (VALID) { \
    _Pragma("unroll") \
    for (int q_ = 0; q_ < 4; ++q_) { \
      float ex_[8]; \
      ex_[0] = __expf(ar[2 * q_].x);     ex_[1] = __expf(ar[2 * q_].y); \
      ex_[2] = __expf(ar[2 * q_].z);     ex_[3] = __expf(ar[2 * q_].w); \
      ex_[4] = __expf(ar[2 * q_ + 1].x); ex_[5] = __expf(ar[2 * q_ + 1].y); \
      ex_[6] = __expf(ar[2 * q_ + 1].z); ex_[7] = __expf(ar[2 * q_ + 1].w); \
      psum += ((ex_[0] + ex_[1]) + (ex_[2] + ex_[3])) \
            + ((ex_[4] + ex_[5]) + (ex_[6] + ex_[7])); \
      ushort8 wv_; \
      _Pragma("unroll") \
      for (int m_ = 0; m_ < 8; ++m_) wv_[m_] = f2bf(ex_[m_]); \
      *reinterpret_cast<ushort8*>(&As[BUF][rA * BK + (((kh * 4 + q_) ^ (rA & 7)) << 3)]) = wv_; \
    } \
  } } while (0)

// one phase: [stage work || 8 ds_read] barrier; lgkm(0); setprio; 16 MFMA; barrier
#define PHASE(RB, RH, KH, ...) do { \
    __VA_ARGS__ \
    short8 a_[4], b_[4]; \
    _Pragma("unroll") \
    for (int ii = 0; ii < 4; ++ii) { \
      const int ra_ = wm * 128 + ((RH) * 4 + ii) * 16 + l15; \
      a_[ii] = *reinterpret_cast<const short8*>( \
          &As[RB][ra_ * BK + ((((KH) * 4 + ksl) ^ (l15 & 7)) << 3)]); \
      const int rb_ = wn * 64 + ii * 16 + l15; \
      b_[ii] = *reinterpret_cast<const short8*>( \
          &Bs[RB][rb_ * BK + ((((KH) * 4 + ksl) ^ (l15 & 7)) << 3)]); \
    } \
    __builtin_amdgcn_sched_barrier(0); \
    __builtin_amdgcn_s_barrier(); \
    asm volatile("s_waitcnt lgkmcnt(0)" ::: "memory"); \
    __builtin_amdgcn_sched_barrier(0); \
    __builtin_amdgcn_s_setprio(1); \
    _Pragma("unroll") \
    for (int ii = 0; ii < 4; ++ii) \
      _Pragma("unroll") \
      for (int jj = 0; jj < 4; ++jj) \
        acc[(RH) * 4 + ii][jj] = __builtin_amdgcn_mfma_f32_16x16x32_bf16( \
            a_[ii], b_[jj], acc[(RH) * 4 + ii][jj], 0, 0, 0); \
    __builtin_amdgcn_s_setprio(0); \
    __builtin_amdgcn_sched_barrier(0); \
    __builtin_amdgcn_s_barrier(); \
  } while (0)

// one K-tile = 4 phases. Counted vmcnt: vmcnt(4) @phase2 (A(t+1) regs ready,
// B(t+1) gloads stay in flight); vmcnt(8) @phase3 after issuing A(t+2)
// (B(t+1) ready for next tile, A(t+2) stays in flight). Never 0 in the loop.
#define TILE(T, RB, SBUF) do { \
    PHASE(RB, 0, 0, SBST((T) + 1, SBUF); ); \
    PHASE(RB, 0, 1, ; ); \
    PHASE(RB, 1, 0, \
        asm volatile("s_waitcnt vmcnt(4)" ::: "memory"); \
        __builtin_amdgcn_sched_barrier(0); \
        EXPWRITE((T) + 1 < NT, SBUF); ); \
    PHASE(RB, 1, 1, \
        LOADA((T) + 2); \
        asm volatile("s_waitcnt vmcnt(8)" ::: "memory"); \
        __builtin_amdgcn_sched_barrier(0); ); \
  } while (0)

__global__ __launch_bounds__(512, 2) void gemm_kernel(const float* __restrict__ e,
                                                      const unsigned short* __restrict__ sT,
                                                      float* __restrict__ out) {
  __shared__ __align__(16) unsigned short As[2][BM * BK];  // 64 KiB
  __shared__ __align__(16) unsigned short Bs[2][BN * BK];  // 64 KiB
  __shared__ float sArr[BM];                               // 1 KiB

  // T1 bijective XCD swizzle (NWG % 8 == 0); n-tile fastest so the 3 blocks
  // sharing an e-panel are adjacent on one XCD; 12 blocks = one batch.
  const int orig = blockIdx.x;
  const int wgid = (orig & 7) * (NWG / 8) + (orig >> 3);
  const int b    = wgid / (MT * NTL);
  const int rem  = wgid % (MT * NTL);
  const int m0   = (rem / NTL) * BM;
  const int n0   = (rem % NTL) * BN;

  const int t    = threadIdx.x;
  const int lane = t & 63;
  const int w    = t >> 6;           // 0..7
  const int wm   = w >> 2;           // 0..1 (M): rows wm*128..+127
  const int wn   = w & 3;            // 0..3 (N): cols wn*64..+63
  const int l15  = lane & 15;
  const int ksl  = lane >> 4;        // frag k-slot 0..3

  // A staging: thread owns e-row rA, k-half kh (32 consecutive floats/K-tile)
  const int rA = t >> 1;             // 0..255
  const int kh = t & 1;

  // B staging: per-lane inverse-swizzled source slot (slot = (lane&7) ^ row&7)
  const int brow  = lane >> 3;               // 0..7
  const int bslot = (lane & 7) ^ brow;

  const float*          Ae   = e  + ((size_t)b * L2_ + m0) * L1_;
  const unsigned short* Bb   = sT + ((size_t)b * D_  + n0) * L1_;
  const unsigned short* Bsrc = Bb + (size_t)(w * 8 + brow) * L1_ + bslot * 8;
  const float*          Asrc = Ae + (size_t)rA * L1_ + kh * 32;

  f32x4 acc[8][4] = {};
  float4 ar[8];
  float psum = 0.f;

  // prologue: A(0) regs -> exp -> As[0]; B(0) gloads; A(1) regs in flight.
  LOADA(0);
  SBST(0, 0);
  EXPWRITE(1, 0);            // compiler auto-vmcnt drains LOADA(0) only (B(0) younger)
  LOADA(1);
  asm volatile("s_waitcnt vmcnt(8)" ::: "memory");   // B(0) resident; A(1) in flight
  asm volatile("s_waitcnt lgkmcnt(0)" ::: "memory"); // publish As[0]
  __builtin_amdgcn_s_barrier();

#pragma unroll
  for (int kt = 0; kt < NT; kt += 2) {
    TILE(kt,     0, 1);
    TILE(kt + 1, 1, 0);
  }

  // row-sum: thread pair (t, t^1) holds complementary k-halves of row rA
  psum += __shfl_xor(psum, 1);
  if ((lane & 1) == 0) sArr[rA] = psum;
  __syncthreads();

  // epilogue: C/D layout col=lane&15, row=(lane>>4)*4+reg; scale by 1/rowsum
  const int rbase = (lane >> 4) << 2;
  float* Cb = out + ((size_t)b * L2_ + m0 + wm * 128) * D_ + n0 + wn * 64;
#pragma unroll
  for (int i = 0; i < 8; ++i) {
    float inv[4];
#pragma unroll
    for (int r = 0; r < 4; ++r)
      inv[r] = 1.0f / sArr[wm * 128 + i * 16 + rbase + r];
#pragma unroll
    for (int jj = 0; jj < 4; ++jj)
#pragma unroll
      for (int r = 0; r < 4; ++r)
        Cb[(size_t)(i * 16 + rbase + r) * D_ + jj * 16 + l15] = acc[i][jj][r] * inv[r];
  }
}

extern "C" void kernel_launch(void* const* d_in, const int* in_sizes, int n_in,
                              void* d_out, int out_size, void* d_ws, size_t ws_size,
                              hipStream_t stream) {
  const float* sent = (const float*)d_in[0];
  const float* e    = (const float*)d_in[1];
  float* out = (float*)d_out;

  unsigned short* sT = (unsigned short*)d_ws;

  transpose_cast_kernel<<<dim3(D_ / 64, L1_ / 64, B_), 256, 0, stream>>>(sent, sT);
  gemm_kernel<<<dim3(NWG), 512, 0, stream>>>(e, sT, out);
}

// Round 2
// 283.560 us; speedup vs baseline: 2.6087x; 2.6087x over previous
//
#include <hip/hip_runtime.h>
#include <hip/hip_bf16.h>

// Problem: out[b,q,d] = softmax(e[b,q,:]) @ sent[b,:,d]
// B=64, L2=1024, L1=1024, D=768, fp32 in/out.
// Softmax fused into GEMM via shift-invariance:
//   out = (exp(e) @ sent) / rowsum(exp(e))      (e ~ N(0,1): no overflow)
// Workspace: sT (bf16) [B][D][L1] @ 0 (100,663,296 B)
//
// GEMM: 128x256 tile, BK=64, 2-phase/K-tile schedule (T2 XOR swizzle +
// T3/T4 counted vmcnt + T5 setprio), exp fused into reg-staged A path.
// Per-wave 64x64 out -> acc[4][4]=64 regs (round-1's acc[8][4]=128 spilled:
// WRITE_SIZE 202->903 MB of scratch. Keep accumulator <= 64.)

#define B_  64
#define L1_ 1024
#define L2_ 1024
#define D_  768

typedef __attribute__((ext_vector_type(8))) short short8;
typedef __attribute__((ext_vector_type(4))) float f32x4;
typedef __attribute__((ext_vector_type(8))) unsigned short ushort8;

static __device__ __forceinline__ unsigned short f2bf(float x) {
  union { float f; unsigned int u; } c; c.f = x;
  unsigned int r = c.u + 0x7FFF + ((c.u >> 16) & 1);  // RNE
  return (unsigned short)(r >> 16);
}

// ---------------- transpose + cast: sent[b][l][d] f32 -> sT[b][d][l] bf16 ---
__global__ __launch_bounds__(256) void transpose_cast_kernel(const float* __restrict__ sent,
                                                             unsigned short* __restrict__ sT) {
  __shared__ unsigned short tile[64][66];
  const int b  = blockIdx.z;
  const int l0 = blockIdx.y << 6;
  const int d0 = blockIdx.x << 6;
  const int t  = threadIdx.x;
  const float* sp = sent + ((size_t)b * L1_ + l0) * D_ + d0;
  const int c4 = (t & 15) << 2;
  const int r0 = t >> 4;
#pragma unroll
  for (int p = 0; p < 4; ++p) {
    const int r = r0 + (p << 4);
    float4 v = *reinterpret_cast<const float4*>(sp + (size_t)r * D_ + c4);
    tile[r][c4 + 0] = f2bf(v.x);
    tile[r][c4 + 1] = f2bf(v.y);
    tile[r][c4 + 2] = f2bf(v.z);
    tile[r][c4 + 3] = f2bf(v.w);
  }
  __syncthreads();
  unsigned short* op = sT + ((size_t)b * D_ + d0) * L1_ + l0;
  const int l8  = (t & 7) << 3;
  const int dd0 = t >> 3;
#pragma unroll
  for (int p = 0; p < 2; ++p) {
    const int d = dd0 + (p << 5);
    ushort8 w;
#pragma unroll
    for (int j = 0; j < 8; ++j) w[j] = tile[l8 + j][d];
    *reinterpret_cast<ushort8*>(op + (size_t)d * L1_ + l8) = w;
  }
}

// ------- fused GEMM: out[b] = (exp(e[b]) @ sT[b]^T) / rowsum(exp(e[b])) ----
#define BM 128
#define BN 256
#define BK 64
#define NT    (L1_ / BK)              // 16 K-tiles
#define MT    (L2_ / BM)              // 8
#define NTL   (D_ / BN)               // 3
#define NWG   (B_ * MT * NTL)         // 1536 (divisible by 8)

#define GLOAD(gp, lp) \
  __builtin_amdgcn_global_load_lds((const __attribute__((address_space(1))) char*)(gp), \
                                   (__attribute__((address_space(3))) char*)(lp), 16, 0, 0)

// stage B K-tile T into Bs[BUF]: linear LDS dest, inverse-swizzled source.
// 4 rounds x (512 thr x 16B) = 32 KiB. Per-lane source slot precomputed (Bsrc).
#define SBST(T, BUF) do { \
    const int _tb = (T) & (NT - 1); \
    _Pragma("unroll") \
    for (int c_ = 0; c_ < 4; ++c_) \
      GLOAD(Bsrc + (size_t)c_ * 64 * L1_ + _tb * BK, &Bs[BUF][(c_ * 64 + w * 8) * BK]); \
  } while (0)

// A K-tile T f32 loads -> regs (thread owns row rA, k-quarter kq: 16 floats)
#define LOADA(T) do { \
    const int _ta = (T) & (NT - 1); \
    _Pragma("unroll") \
    for (int j_ = 0; j_ < 4; ++j_) \
      ar[j_] = *reinterpret_cast<const float4*>(Asrc + _ta * BK + j_ * 4); \
  } while (0)

// exp + cvt + swizzled ds_write of the A regs into As[BUF]; row-partial psum.
#define EXPWRITE(VALID, BUF) do { if (VALID) { \
    _Pragma("unroll") \
    for (int q_ = 0; q_ < 2; ++q_) { \
      float ex_[8]; \
      ex_[0] = __expf(ar[2 * q_].x);     ex_[1] = __expf(ar[2 * q_].y); \
      ex_[2] = __expf(ar[2 * q_].z);     ex_[3] = __expf(ar[2 * q_].w); \
      ex_[4] = __expf(ar[2 * q_ + 1].x); ex_[5] = __expf(ar[2 * q_ + 1].y); \
      ex_[6] = __expf(ar[2 * q_ + 1].z); ex_[7] = __expf(ar[2 * q_ + 1].w); \
      psum += ((ex_[0] + ex_[1]) + (ex_[2] + ex_[3])) \
            + ((ex_[4] + ex_[5]) + (ex_[6] + ex_[7])); \
      ushort8 wv_; \
      _Pragma("unroll") \
      for (int m_ = 0; m_ < 8; ++m_) wv_[m_] = f2bf(ex_[m_]); \
      *reinterpret_cast<ushort8*>(&As[BUF][rA * BK + (((kq * 2 + q_) ^ (rA & 7)) << 3)]) = wv_; \
    } \
  } } while (0)

// one phase: [stage work || 8 ds_read] barrier; lgkm(0); setprio; 16 MFMA; barrier
#define PHASE(RB, KH, ...) do { \
    __VA_ARGS__ \
    short8 a_[4], b_[4]; \
    _Pragma("unroll") \
    for (int ii = 0; ii < 4; ++ii) { \
      const int ra_ = wm * 64 + ii * 16 + l15; \
      a_[ii] = *reinterpret_cast<const short8*>( \
          &As[RB][ra_ * BK + ((((KH) * 4 + ksl) ^ (l15 & 7)) << 3)]); \
      const int rb_ = wn * 64 + ii * 16 + l15; \
      b_[ii] = *reinterpret_cast<const short8*>( \
          &Bs[RB][rb_ * BK + ((((KH) * 4 + ksl) ^ (l15 & 7)) << 3)]); \
    } \
    __builtin_amdgcn_sched_barrier(0); \
    __builtin_amdgcn_s_barrier(); \
    asm volatile("s_waitcnt lgkmcnt(0)" ::: "memory"); \
    __builtin_amdgcn_sched_barrier(0); \
    __builtin_amdgcn_s_setprio(1); \
    _Pragma("unroll") \
    for (int ii = 0; ii < 4; ++ii) \
      _Pragma("unroll") \
      for (int jj = 0; jj < 4; ++jj) \
        acc[ii][jj] = __builtin_amdgcn_mfma_f32_16x16x32_bf16( \
            a_[ii], b_[jj], acc[ii][jj], 0, 0, 0); \
    __builtin_amdgcn_s_setprio(0); \
    __builtin_amdgcn_sched_barrier(0); \
    __builtin_amdgcn_s_barrier(); \
  } while (0)

// one K-tile = 2 phases. Counted vmcnt, never 0 in the loop:
//  P0: issue B(t+1) gloads (4/thread).
//  P1: vmcnt(4) -> A(t+1) f32 regs ready (B gloads stay in flight);
//      EXPWRITE(t+1); issue A(t+2) loads; vmcnt(4) -> B(t+1) resident
//      (A(t+2) stays in flight).
#define TILE(T, RB, SBUF) do { \
    PHASE(RB, 0, SBST((T) + 1, SBUF); ); \
    PHASE(RB, 1, \
        asm volatile("s_waitcnt vmcnt(4)" ::: "memory"); \
        __builtin_amdgcn_sched_barrier(0); \
        EXPWRITE((T) + 1 < NT, SBUF); \
        LOADA((T) + 2); \
        asm volatile("s_waitcnt vmcnt(4)" ::: "memory"); \
        __builtin_amdgcn_sched_barrier(0); ); \
  } while (0)

__global__ __launch_bounds__(512, 2) void gemm_kernel(const float* __restrict__ e,
                                                      const unsigned short* __restrict__ sT,
                                                      float* __restrict__ out) {
  __shared__ __align__(16) unsigned short As[2][BM * BK];  // 32 KiB
  __shared__ __align__(16) unsigned short Bs[2][BN * BK];  // 64 KiB
  __shared__ float sArr[BM];                               // 0.5 KiB

  // T1 bijective XCD swizzle (NWG % 8 == 0); n-tile fastest so the 3 blocks
  // sharing an e-panel are adjacent on one XCD; 24 blocks = one batch.
  const int orig = blockIdx.x;
  const int wgid = (orig & 7) * (NWG / 8) + (orig >> 3);
  const int b    = wgid / (MT * NTL);
  const int rem  = wgid % (MT * NTL);
  const int m0   = (rem / NTL) * BM;
  const int n0   = (rem % NTL) * BN;

  const int t    = threadIdx.x;
  const int lane = t & 63;
  const int w    = t >> 6;           // 0..7
  const int wm   = w >> 2;           // 0..1 (M): rows wm*64..+63
  const int wn   = w & 3;            // 0..3 (N): cols wn*64..+63
  const int l15  = lane & 15;
  const int ksl  = lane >> 4;        // frag k-slot 0..3

  // A staging: thread owns e-row rA (4 threads/row), k-quarter kq (16 floats)
  const int rA = t >> 2;             // 0..127
  const int kq = t & 3;

  // B staging: per-lane inverse-swizzled source slot (slot = (lane&7) ^ row&7)
  const int brow  = lane >> 3;               // 0..7
  const int bslot = (lane & 7) ^ brow;

  const float*          Ae   = e  + ((size_t)b * L2_ + m0) * L1_;
  const unsigned short* Bb   = sT + ((size_t)b * D_  + n0) * L1_;
  const unsigned short* Bsrc = Bb + (size_t)(w * 8 + brow) * L1_ + bslot * 8;
  const float*          Asrc = Ae + (size_t)rA * L1_ + kq * 16;

  f32x4 acc[4][4] = {};
  float4 ar[4];
  float psum = 0.f;

  // prologue: A(0) regs -> exp -> As[0]; B(0) gloads; A(1) regs in flight.
  LOADA(0);
  SBST(0, 0);
  EXPWRITE(1, 0);            // compiler auto-vmcnt drains LOADA(0) only (B(0) younger)
  LOADA(1);
  asm volatile("s_waitcnt vmcnt(4)" ::: "memory");   // B(0) resident; A(1) in flight
  asm volatile("s_waitcnt lgkmcnt(0)" ::: "memory"); // publish As[0]
  __builtin_amdgcn_s_barrier();

#pragma unroll 1
  for (int kt = 0; kt < NT; kt += 2) {
    TILE(kt,     0, 1);
    TILE(kt + 1, 1, 0);
  }

  // row-sum: 4 threads/row hold complementary k-quarters
  psum += __shfl_xor(psum, 1);
  psum += __shfl_xor(psum, 2);
  if ((lane & 3) == 0) sArr[rA] = psum;
  __syncthreads();

  // epilogue: C/D layout col=lane&15, row=(lane>>4)*4+reg; scale by 1/rowsum
  const int rbase = (lane >> 4) << 2;
  float* Cb = out + ((size_t)b * L2_ + m0 + wm * 64) * D_ + n0 + wn * 64;
#pragma unroll
  for (int i = 0; i < 4; ++i) {
    float inv[4];
#pragma unroll
    for (int r = 0; r < 4; ++r)
      inv[r] = 1.0f / sArr[wm * 64 + i * 16 + rbase + r];
#pragma unroll
    for (int jj = 0; jj < 4; ++jj)
#pragma unroll
      for (int r = 0; r < 4; ++r)
        Cb[(size_t)(i * 16 + rbase + r) * D_ + jj * 16 + l15] = acc[i][jj][r] * inv[r];
  }
}

extern "C" void kernel_launch(void* const* d_in, const int* in_sizes, int n_in,
                              void* d_out, int out_size, void* d_ws, size_t ws_size,
                              hipStream_t stream) {
  const float* sent = (const float*)d_in[0];
  const float* e    = (const float*)d_in[1];
  float* out = (float*)d_out;

  unsigned short* sT = (unsigned short*)d_ws;

  transpose_cast_kernel<<<dim3(D_ / 64, L1_ / 64, B_), 256, 0, stream>>>(sent, sT);
  gemm_kernel<<<dim3(NWG), 512, 0, stream>>>(e, sT, out);
}

// Round 3
// 261.107 us; speedup vs baseline: 2.8331x; 1.0860x over previous
//
#include <hip/hip_runtime.h>
#include <hip/hip_bf16.h>

// Problem: out[b,q,d] = softmax(e[b,q,:]) @ sent[b,:,d]
// B=64, L2=1024, L1=1024, D=768, fp32 in/out.
// Softmax fused into GEMM via shift-invariance:
//   out = (exp(e) @ sent) / rowsum(exp(e))      (e ~ N(0,1): no overflow)
// Workspace: sT (bf16) [B][D][L1] @ 0 (100,663,296 B)
//
// Round-3: round-0's proven ring structure, ring-3 -> ring-2.
// LDS 72.5 KiB -> 48.5 KiB => 3 blocks/CU (24 waves/CU vs 16) for more
// cross-block TLP to fill barrier-drain + exp-VALU stalls.
// Ring-2 drain discipline: B(kt+1) issued at top of iter kt MUST be
// vmcnt-drained by every wave before iter kt's trailing barrier (cross-wave
// LDS publication) -> tail wait is vmcnt(2) lgkmcnt(0) (LOADA(kt+2) stays in
// flight; LOADA unguarded/wrapped so the vmcnt count is static at the tail).

#define B_  64
#define L1_ 1024
#define L2_ 1024
#define D_  768

typedef __attribute__((ext_vector_type(8))) short short8;
typedef __attribute__((ext_vector_type(4))) float f32x4;
typedef __attribute__((ext_vector_type(8))) unsigned short ushort8;

static __device__ __forceinline__ unsigned short f2bf(float x) {
  union { float f; unsigned int u; } c; c.f = x;
  unsigned int r = c.u + 0x7FFF + ((c.u >> 16) & 1);  // RNE
  return (unsigned short)(r >> 16);
}

// ---------------- transpose + cast: sent[b][l][d] f32 -> sT[b][d][l] bf16 ---
__global__ __launch_bounds__(256) void transpose_cast_kernel(const float* __restrict__ sent,
                                                             unsigned short* __restrict__ sT) {
  __shared__ unsigned short tile[64][66];
  const int b  = blockIdx.z;
  const int l0 = blockIdx.y << 6;
  const int d0 = blockIdx.x << 6;
  const int t  = threadIdx.x;
  const float* sp = sent + ((size_t)b * L1_ + l0) * D_ + d0;
  const int c4 = (t & 15) << 2;
  const int r0 = t >> 4;
#pragma unroll
  for (int p = 0; p < 4; ++p) {
    const int r = r0 + (p << 4);
    float4 v = *reinterpret_cast<const float4*>(sp + (size_t)r * D_ + c4);
    tile[r][c4 + 0] = f2bf(v.x);
    tile[r][c4 + 1] = f2bf(v.y);
    tile[r][c4 + 2] = f2bf(v.z);
    tile[r][c4 + 3] = f2bf(v.w);
  }
  __syncthreads();
  unsigned short* op = sT + ((size_t)b * D_ + d0) * L1_ + l0;
  const int l8  = (t & 7) << 3;
  const int dd0 = t >> 3;
#pragma unroll
  for (int p = 0; p < 2; ++p) {
    const int d = dd0 + (p << 5);
    ushort8 w;
#pragma unroll
    for (int j = 0; j < 8; ++j) w[j] = tile[l8 + j][d];
    *reinterpret_cast<ushort8*>(op + (size_t)d * L1_ + l8) = w;
  }
}

// ------- fused GEMM: out[b] = (exp(e[b]) @ sT[b]^T) / rowsum(exp(e[b])) ----
// Ring-2, BK=32, 128x256 tile. LDS 48.5 KiB -> 3 blocks/CU.
// 8 waves (2M x 4N), per-wave 64x64 out.
#define BM 128
#define BN 256
#define BK 32
#define NT    (L1_ / BK)              // 32
#define NTILE (D_ / BN)               // 3
#define MTILE (L2_ / BM)              // 8
#define NWG   (NTILE * MTILE * B_)    // 1536 (divisible by 8)

// 4 16B-slots per 64B row; per-parity-class perfect XOR swizzle
#define SW(r) ((((r) >> 2) ^ (r)) & 3)

#define GLOAD(gp, lp) \
  __builtin_amdgcn_global_load_lds((const __attribute__((address_space(1))) char*)(gp), \
                                   (__attribute__((address_space(3))) char*)(lp), 16, 0, 0)

// load A e-tile (f32) into regs: 8 f32 per thread (2 float4); 4 threads/row.
// Unguarded (index wraps) so vmcnt counts stay static at the tail.
#define LOADA(T) do { const int _ta = (T) & (NT - 1);                                        \
    aregs[0] = *reinterpret_cast<const float4*>(Ae + (size_t)rA * L1_ + _ta * BK + cA);      \
    aregs[1] = *reinterpret_cast<const float4*>(Ae + (size_t)rA * L1_ + _ta * BK + cA + 4);  \
  } while (0)

// exp + cvt + swizzled LDS write of A tile T (regs loaded one iter earlier);
// accumulates thread-local row partial sum. MUST stay guarded (psum!).
#define EXPWRITE(T) do { if ((T) < NT) {                                        \
    unsigned short* Ad_ = &As[(T) & 1][0];                                      \
    float ex_[8];                                                               \
    ex_[0] = __expf(aregs[0].x); ex_[1] = __expf(aregs[0].y);                   \
    ex_[2] = __expf(aregs[0].z); ex_[3] = __expf(aregs[0].w);                   \
    ex_[4] = __expf(aregs[1].x); ex_[5] = __expf(aregs[1].y);                   \
    ex_[6] = __expf(aregs[1].z); ex_[7] = __expf(aregs[1].w);                   \
    psum += ((ex_[0] + ex_[1]) + (ex_[2] + ex_[3]))                             \
          + ((ex_[4] + ex_[5]) + (ex_[6] + ex_[7]));                            \
    ushort8 w0_;                                                                \
    _Pragma("unroll")                                                           \
    for (int q_ = 0; q_ < 8; ++q_) w0_[q_] = f2bf(ex_[q_]);                     \
    *reinterpret_cast<ushort8*>(&Ad_[rA * BK + aslot * 8]) = w0_;               \
  } } while (0)

// stage B tile via global_load_lds: linear dest, inverse-swizzled source
#define SB(T) do { if ((T) < NT) {                                              \
    GLOAD(Bb + (size_t)rB0 * L1_ + (T) * BK + sB0, &Bs[(T) & 1][(w * 32) * BK]);      \
    GLOAD(Bb + (size_t)rB1 * L1_ + (T) * BK + sB1, &Bs[(T) & 1][(w * 32 + 16) * BK]); \
  } } while (0)

__global__ __launch_bounds__(512, 2) void gemm_kernel(const float* __restrict__ e,
                                                      const unsigned short* __restrict__ sT,
                                                      float* __restrict__ out) {
  __shared__ __align__(16) unsigned short As[2][BM * BK];  // 16 KiB
  __shared__ __align__(16) unsigned short Bs[2][BN * BK];  // 32 KiB
  __shared__ float sArr[BM];                               // 0.5 KiB

  // T1 bijective XCD swizzle; n-tile fastest within a 192-chunk (3 n-blocks
  // sharing an A e-panel adjacent; one batch = 24 blocks, sT[b] L2-resident).
  const int orig = blockIdx.x;
  const int wgid = (orig & 7) * (NWG / 8) + (orig >> 3);
  const int b    = wgid / (NTILE * MTILE);
  const int rem  = wgid % (NTILE * MTILE);
  const int m0   = (rem / NTILE) * BM;
  const int n0   = (rem % NTILE) * BN;

  const int t    = threadIdx.x;
  const int lane = t & 63;
  const int w    = t >> 6;           // 0..7
  const int wm   = w >> 2;           // 0..1 (M)
  const int wn   = w & 3;            // 0..3 (N)
  const int l15  = lane & 15;
  const int ksl  = lane >> 4;        // frag k-slot 0..3
  const int rA   = w * 16 + (lane >> 2);        // A-stage row (4 lanes/row)
  const int cA   = (lane & 3) * 8;              // A-stage col base (f32)
  const int aslot = (lane & 3) ^ SW(rA);        // A-stage swizzled slot
  const int rB0  = w * 32 + (lane >> 2);        // B-stage rows
  const int rB1  = rB0 + 16;
  const int sB0  = ((lane & 3) ^ SW(rB0)) * 8;  // B source slots (elems)
  const int sB1  = ((lane & 3) ^ SW(rB1)) * 8;

  const float*          Ae = e  + ((size_t)b * L2_ + m0) * L1_;
  const unsigned short* Bb = sT + ((size_t)b * D_  + n0) * L1_;

  f32x4 acc[4][4] = {};
  float4 aregs[2];
  float psum = 0.f;

  // prologue: A(0) regs; B(0) in flight; exp+write A(0); A(1) regs.
  LOADA(0);
  SB(0);
  EXPWRITE(0);               // compiler auto-vmcnt drains LOADA(0) only (SB(0) newer)
  LOADA(1);
  asm volatile("s_waitcnt vmcnt(2) lgkmcnt(0)" ::: "memory");  // B(0) done; LOADA(1) in flight
  __builtin_amdgcn_s_barrier();
  __builtin_amdgcn_sched_barrier(0);

  for (int kt = 0; kt < NT; ++kt) {
    SB(kt + 1);              // buf (kt+1)&1 was freed at end of iter kt-1
    EXPWRITE(kt + 1);        // auto-vmcnt drains LOADA(kt+1) (oldest in queue)
    LOADA(kt + 2);

    const unsigned short* Apt = As[kt & 1];
    const unsigned short* Bpt = Bs[kt & 1];
    short8 a[4], bb[4];
    __builtin_amdgcn_s_setprio(1);
#pragma unroll
    for (int i = 0; i < 4; ++i) {
      const int ra = wm * 64 + i * 16 + l15;
      a[i] = *reinterpret_cast<const short8*>(&Apt[ra * BK + ((ksl ^ SW(ra)) << 3)]);
      const int rb = wn * 64 + i * 16 + l15;
      bb[i] = *reinterpret_cast<const short8*>(&Bpt[rb * BK + ((ksl ^ SW(rb)) << 3)]);
    }
#pragma unroll
    for (int i = 0; i < 4; ++i)
#pragma unroll
      for (int jn = 0; jn < 4; ++jn)
        acc[i][jn] = __builtin_amdgcn_mfma_f32_16x16x32_bf16(a[i], bb[jn], acc[i][jn], 0, 0, 0);
    __builtin_amdgcn_s_setprio(0);

    if (kt < NT - 1) {
      // vmcnt(2): SB(kt+1) drained by EVERY wave before the barrier (cross-
      // wave LDS publication for next iter's frag reads); LOADA(kt+2) stays
      // in flight. lgkmcnt(0): frag ds_reads + EXPWRITE ds_writes drained.
      asm volatile("s_waitcnt vmcnt(2) lgkmcnt(0)" ::: "memory");
      __builtin_amdgcn_s_barrier();
      __builtin_amdgcn_sched_barrier(0);
    }
  }

  // row-sum: 4 threads/row hold complementary k-quarters
  psum += __shfl_xor(psum, 1);
  psum += __shfl_xor(psum, 2);
  if ((lane & 3) == 0) sArr[rA] = psum;
  __syncthreads();

  // epilogue: C/D layout col=lane&15, row=(lane>>4)*4+reg; scale by 1/s
  const int rbase = (lane >> 4) << 2;
  float* Cb = out + ((size_t)b * L2_ + m0 + wm * 64) * D_ + n0 + wn * 64;
#pragma unroll
  for (int i = 0; i < 4; ++i) {
    float inv[4];
#pragma unroll
    for (int r = 0; r < 4; ++r)
      inv[r] = 1.0f / sArr[wm * 64 + i * 16 + rbase + r];
#pragma unroll
    for (int jn = 0; jn < 4; ++jn)
#pragma unroll
      for (int r = 0; r < 4; ++r)
        Cb[(size_t)(i * 16 + rbase + r) * D_ + jn * 16 + l15] = acc[i][jn][r] * inv[r];
  }
}

extern "C" void kernel_launch(void* const* d_in, const int* in_sizes, int n_in,
                              void* d_out, int out_size, void* d_ws, size_t ws_size,
                              hipStream_t stream) {
  const float* sent = (const float*)d_in[0];
  const float* e    = (const float*)d_in[1];
  float* out = (float*)d_out;

  unsigned short* sT = (unsigned short*)d_ws;

  transpose_cast_kernel<<<dim3(D_ / 64, L1_ / 64, B_), 256, 0, stream>>>(sent, sT);
  gemm_kernel<<<dim3(NWG), 512, 0, stream>>>(e, sT, out);
}